// Round 16
// baseline (252.936 us; speedup 1.0000x reference)
//
#include <hip/hip_runtime.h>
#include <hip/hip_bf16.h>

// ---------------------------------------------------------------------------
// GatedAttentionFusion on MI355X (gfx950). Inputs bf16 OR fp32 (ballot-probe).
//   SRC_LENS = {2048,1536,1800,1200} (sum 6584), REF_LENS = {1900,2048,1400,1600}
// R28 == R27 resubmitted (R27 bench was a GPUAcquisitionTimeout; no data).
// R27: (a) PROBE: flash_all split into two z-launches (~33us each) so any
// non-flash kernel >33us surfaces in top-5 (4 neutral rounds at 236-240;
// ~60-80us of the ~173us non-flash remainder is unattributed).
// (b) WIN: HID never materialized. HID=relu(ALN@gw1+gb1) feeds ONLY the
// rank-1 gw2 dot -> gate_gemm computes per-col-block partial dots in its
// epilogue (relu in-reg, *gw2, shfl_xor l15-reduce, 2-wave LDS combine,
// deterministic z4[4][6592] write, no atomics). finalize reads 4 f32/row.
// Saves 13.5MB HID write + 13.5MB read + finalize dot work.
// Flash core unchanged (R22 form). proj2/pv (R24 form) unchanged.
// Tiers: A2 (split-K flash + fused-combine w_out GEMM) / A / B / sentinel.
// ---------------------------------------------------------------------------

typedef __bf16 bf16x8_t __attribute__((ext_vector_type(8)));
typedef __bf16 bf16x4_t __attribute__((ext_vector_type(4)));
typedef float f32x4_t __attribute__((ext_vector_type(4)));
typedef float f32x2_t __attribute__((ext_vector_type(2)));

#define CQ_SCALE 0.18033688011112042f  // 0.125 * log2(e)

__device__ inline bf16x8_t zero8() {
  bf16x8_t z;
#pragma unroll
  for (int t = 0; t < 8; ++t) z[t] = (__bf16)0.0f;
  return z;
}

// wave-uniform: 1 if the tensor behind w is fp32, 0 if bf16.
__device__ __forceinline__ int sniff_f32(const void* w) {
  unsigned short u = ((const unsigned short*)w)[threadIdx.x & 63];
  return __ballot((u & 0x7F80) >= 0x3F80) != 0ULL;
}

// chunked XCD swizzle: XCD k (= bid mod 8) gets contiguous panel-major work.
// nwg must be divisible by 8. Returns (bx, by).
__device__ __forceinline__ int2 swz(int bid, int nwg, int nby) {
  int chunk = nwg >> 3;
  int w = (bid & 7) * chunk + (bid >> 3);
  return make_int2(w / nby, w % nby);
}

__global__ void sentinel_k(float* out) {
  if (threadIdx.x == 0 && blockIdx.x == 0) out[0] = 1000.0f;  // ws too small
}

// Fused conversion kernel. do_feats: blocks [0,3383) convert feats (x8
// vectorized) into the R3/P overlay; remaining blocks grid-stride the
// weight tensors. do_feats==0: all blocks do weights.
__global__ void cv_all(const void* w_in, const void* b_in, const void* w_out,
                       const void* b_out, const void* gw1, const void* gb1,
                       const void* gw2, const void* gb2,
                       __hip_bfloat16* __restrict__ ws,
                       const void* fs, const void* fr, int do_feats) {
  int f = sniff_f32(w_in);
  int bid = blockIdx.x;
  if (do_feats && bid < 3383) {
    // feats -> bf16: FS at el 11,803,680 (6584x512); FR at el 15,174,688.
    int i = bid * 256 + threadIdx.x;
    const int NFS = 421376;  // 6584*512/8
    const void* src;
    size_t dst;
    int off;
    if (i < NFS) { src = fs; dst = 11803680; off = i * 8; }
    else { src = fr; dst = 15174688; off = (i - NFS) * 8; }
    __hip_bfloat16* d = ws + dst + off;
    if (f) {
      const float* p = (const float*)src + off;
      bf16x8_t v;
#pragma unroll
      for (int e = 0; e < 8; ++e) v[e] = (__bf16)p[e];
      *reinterpret_cast<bf16x8_t*>(d) = v;
    } else {
      *reinterpret_cast<bf16x8_t*>(d) =
          *reinterpret_cast<const bf16x8_t*>((const __hip_bfloat16*)src + off);
    }
    return;
  }
  int base = do_feats ? 3383 : 0;
  int nb = gridDim.x - base;
  const size_t F_W_IN = 16, F_B_IN = 786448, F_W_OUT = 787984, F_B_OUT = 1050128,
               F_GW1 = 1050640, F_GB1 = 1312784, F_GW2 = 1313296, F_GB2 = 1313808;
  const int total = 1313793;
  for (int g = (bid - base) * 256 + threadIdx.x; g < total; g += nb * 256) {
    const void* src;
    size_t dst;
    int i;
    if (g < 786432) { src = w_in; dst = F_W_IN; i = g; }
    else if (g < 787968) { src = b_in; dst = F_B_IN; i = g - 786432; }
    else if (g < 1050112) { src = w_out; dst = F_W_OUT; i = g - 787968; }
    else if (g < 1050624) { src = b_out; dst = F_B_OUT; i = g - 1050112; }
    else if (g < 1312768) { src = gw1; dst = F_GW1; i = g - 1050624; }
    else if (g < 1313280) { src = gb1; dst = F_GB1; i = g - 1312768; }
    else if (g < 1313792) { src = gw2; dst = F_GW2; i = g - 1313280; }
    else { src = gb2; dst = F_GB2; i = g - 1313792; }
    ws[dst + i] = f ? __float2bfloat16(((const float*)src)[i])
                    : ((const __hip_bfloat16*)src)[i];
  }
}

// ---- shared GEMM core (BM=128, BN=128, BK=64): C = A·Bt + bias -------------
// chs == 0: C row-major [M][ldc].  chs > 0: channel-blocked C[c][row][64]
// with c = col>>6, channel stride chs (elements).
__device__ __forceinline__ void gemm_core(
    const void* __restrict__ A_, long aoff, const __hip_bfloat16* __restrict__ Bt,
    const __hip_bfloat16* __restrict__ bias, __hip_bfloat16* __restrict__ C,
    int M, int K, int lda, int ldc, float cscale, int relu, int f, int bm, int bn,
    long chs, __bf16 (&As)[128][72], __bf16 (&Bs)[128][72]) {
  int tid = threadIdx.x, lane = tid & 63, wave = tid >> 6;
  int wm = wave >> 1, wn = wave & 1;
  int l15 = lane & 15, quad = lane >> 4;

  f32x4_t acc[4][4];
#pragma unroll
  for (int i = 0; i < 4; ++i)
#pragma unroll
    for (int j = 0; j < 4; ++j)
#pragma unroll
      for (int r = 0; r < 4; ++r) acc[i][j][r] = 0.f;

  bf16x8_t ra[4], rb[4];
  f32x4_t raf[4][2];

  auto gload = [&](int k0) {
#pragma unroll
    for (int s = 0; s < 4; ++s) {
      int id = s * 256 + tid;
      int row = id >> 3, col = (id & 7) * 8;
      int arow = bm + row;
      if (f) {
        if (arow < M) {
          const float* p = (const float*)A_ + aoff + (size_t)arow * lda + k0 + col;
          raf[s][0] = *reinterpret_cast<const f32x4_t*>(p);
          raf[s][1] = *reinterpret_cast<const f32x4_t*>(p + 4);
        } else {
#pragma unroll
          for (int e = 0; e < 4; ++e) { raf[s][0][e] = 0.f; raf[s][1][e] = 0.f; }
        }
      } else {
        ra[s] = (arow < M)
                    ? *reinterpret_cast<const bf16x8_t*>((const __hip_bfloat16*)A_ + aoff +
                                                         (size_t)arow * lda + k0 + col)
                    : zero8();
      }
      rb[s] = *reinterpret_cast<const bf16x8_t*>(Bt + (size_t)(bn + row) * 512 + k0 + col);
    }
  };
  auto stage = [&]() {
#pragma unroll
    for (int s = 0; s < 4; ++s) {
      int id = s * 256 + tid;
      int row = id >> 3, col = (id & 7) * 8;
      if (f) {
        bf16x8_t t;
#pragma unroll
        for (int e = 0; e < 4; ++e) {
          t[e] = (__bf16)raf[s][0][e];
          t[4 + e] = (__bf16)raf[s][1][e];
        }
        *reinterpret_cast<bf16x8_t*>(&As[row][col]) = t;
      } else {
        *reinterpret_cast<bf16x8_t*>(&As[row][col]) = ra[s];
      }
      *reinterpret_cast<bf16x8_t*>(&Bs[row][col]) = rb[s];
    }
  };

  int nk = K >> 6;
  gload(0);
  for (int it = 0; it < nk; ++it) {
    stage();
    __syncthreads();
    if (it + 1 < nk) gload((it + 1) * 64);
#pragma unroll
    for (int ks = 0; ks < 2; ++ks) {
      bf16x8_t af[4], bfv[4];
#pragma unroll
      for (int i = 0; i < 4; ++i)
        af[i] = *reinterpret_cast<const bf16x8_t*>(
            &As[wm * 64 + i * 16 + l15][ks * 32 + quad * 8]);
#pragma unroll
      for (int j = 0; j < 4; ++j)
        bfv[j] = *reinterpret_cast<const bf16x8_t*>(
            &Bs[wn * 64 + j * 16 + l15][ks * 32 + quad * 8]);
#pragma unroll
      for (int i = 0; i < 4; ++i)
#pragma unroll
        for (int j = 0; j < 4; ++j)
          acc[i][j] = __builtin_amdgcn_mfma_f32_16x16x32_bf16(af[i], bfv[j], acc[i][j], 0, 0, 0);
    }
    __syncthreads();
  }

#pragma unroll
  for (int i = 0; i < 4; ++i)
#pragma unroll
    for (int j = 0; j < 4; ++j) {
      int col = bn + wn * 64 + j * 16 + l15;
      float bv = __bfloat162float(bias[col]);
#pragma unroll
      for (int r = 0; r < 4; ++r) {
        int row = bm + wm * 64 + i * 16 + quad * 4 + r;
        if (row < M) {
          float v = (acc[i][j][r] + bv) * cscale;
          if (relu) v = fmaxf(v, 0.f);
          size_t idx = chs ? ((size_t)(col >> 6) * chs + (size_t)row * 64 + (col & 63))
                           : ((size_t)row * ldc + col);
          C[idx] = __float2bfloat16(v);
        }
      }
    }
}

// merged Q-proj (208 blocks) + KV-proj (440 blocks); weights from ws (bf16).
// KV written channel-blocked with stride CHS = 6948*64. snf==nullptr -> A bf16.
__global__ __launch_bounds__(256) void proj2(
    const void* __restrict__ fs, const void* __restrict__ fr,
    const __hip_bfloat16* __restrict__ ws, __hip_bfloat16* __restrict__ Q,
    __hip_bfloat16* __restrict__ KV, const void* snf) {
  __shared__ __bf16 As[128][72];
  __shared__ __bf16 Bs[128][72];
  const size_t F_W_IN = 16, F_B_IN = 786448;
  const long CHS = (long)6948 * 64;
  int f = snf ? sniff_f32(snf) : 0;
  int bid = blockIdx.x;
  if (bid < 208) {
    int2 s = swz(bid, 208, 4);  // 52 x 4
    gemm_core(fs, 0, ws + F_W_IN, ws + F_B_IN, Q, 6584, 512, 512, 512, CQ_SCALE, 0, f,
              s.x * 128, s.y * 128, 0, As, Bs);
  } else {
    int2 s = swz(bid - 208, 440, 8);  // 55 x 8
    gemm_core(fr, 0, ws + F_W_IN + 262144, ws + F_B_IN + 512, KV, 6948, 512, 512, 1024,
              1.0f, 0, f, s.x * 128, s.y * 128, CHS, As, Bs);
  }
}

// swizzled 1D-grid GEMM, A bf16, K=512, N=512 (NS=1 w_out path). nwg=208.
__global__ __launch_bounds__(256) void gemm128z(
    const __hip_bfloat16* __restrict__ A, const __hip_bfloat16* __restrict__ Bt,
    const __hip_bfloat16* __restrict__ bias, __hip_bfloat16* __restrict__ C,
    int M, float cscale, int relu) {
  __shared__ __bf16 As[128][72];
  __shared__ __bf16 Bs[128][72];
  int2 s = swz(blockIdx.x, gridDim.x, 4);
  gemm_core(A, 0, Bt, bias, C, M, 512, 512, 512, cscale, relu, 0,
            s.x * 128, s.y * 128, 0, As, Bs);
}

// standalone GEMM (path B), A native (AF32) or bf16, 2D grid.
template <bool AF32>
__global__ __launch_bounds__(256) void gemm128(
    const void* __restrict__ A_, long aoff, const __hip_bfloat16* __restrict__ Bt,
    const __hip_bfloat16* __restrict__ bias, __hip_bfloat16* __restrict__ C,
    int M, int K, int lda, int ldc, float cscale, int relu, long chs,
    const void* snf) {
  __shared__ __bf16 As[128][72];
  __shared__ __bf16 Bs[128][72];
  int f = 0;
  if constexpr (AF32) f = sniff_f32(snf);
  gemm_core(A_, aoff, Bt, bias, C, M, K, lda, ldc, cscale, relu, f,
            blockIdx.x * 128, blockIdx.y * 128, chs, As, Bs);
}

// ---- gate GEMM: z4[cn][row] = sum over this col-block of relu(A@gw1+gb1)*gw2
// No HID materialization. 208 blocks (52x4 swizzled). Deterministic (no
// atomics): l15 shfl_xor reduce -> 2-wave LDS combine -> one write per row.
__global__ __launch_bounds__(256) void gate_gemm(
    const __hip_bfloat16* __restrict__ A, const __hip_bfloat16* __restrict__ Bt,
    const __hip_bfloat16* __restrict__ bias, const __hip_bfloat16* __restrict__ gw2,
    float* __restrict__ z4, int M) {
  __shared__ __bf16 As[128][72];
  __shared__ __bf16 Bs[128][72];
  __shared__ float zsc[128][2];
  int tid = threadIdx.x, lane = tid & 63, wave = tid >> 6;
  int wm = wave >> 1, wn = wave & 1;
  int l15 = lane & 15, quad = lane >> 4;
  int2 sw = swz(blockIdx.x, 208, 4);
  int bm = sw.x * 128, bn = sw.y * 128;

  f32x4_t acc[4][4];
#pragma unroll
  for (int i = 0; i < 4; ++i)
#pragma unroll
    for (int j = 0; j < 4; ++j)
#pragma unroll
      for (int r = 0; r < 4; ++r) acc[i][j][r] = 0.f;

  bf16x8_t ra[4], rb[4];
  auto gload = [&](int k0) {
#pragma unroll
    for (int s = 0; s < 4; ++s) {
      int id = s * 256 + tid;
      int row = id >> 3, col = (id & 7) * 8;
      int arow = bm + row;
      ra[s] = (arow < M)
                  ? *reinterpret_cast<const bf16x8_t*>(A + (size_t)arow * 512 + k0 + col)
                  : zero8();
      rb[s] = *reinterpret_cast<const bf16x8_t*>(Bt + (size_t)(bn + row) * 512 + k0 + col);
    }
  };
  auto stage = [&]() {
#pragma unroll
    for (int s = 0; s < 4; ++s) {
      int id = s * 256 + tid;
      int row = id >> 3, col = (id & 7) * 8;
      *reinterpret_cast<bf16x8_t*>(&As[row][col]) = ra[s];
      *reinterpret_cast<bf16x8_t*>(&Bs[row][col]) = rb[s];
    }
  };

  gload(0);
  for (int it = 0; it < 8; ++it) {
    stage();
    __syncthreads();
    if (it + 1 < 8) gload((it + 1) * 64);
#pragma unroll
    for (int ks = 0; ks < 2; ++ks) {
      bf16x8_t af[4], bfv[4];
#pragma unroll
      for (int i = 0; i < 4; ++i)
        af[i] = *reinterpret_cast<const bf16x8_t*>(
            &As[wm * 64 + i * 16 + l15][ks * 32 + quad * 8]);
#pragma unroll
      for (int j = 0; j < 4; ++j)
        bfv[j] = *reinterpret_cast<const bf16x8_t*>(
            &Bs[wn * 64 + j * 16 + l15][ks * 32 + quad * 8]);
#pragma unroll
      for (int i = 0; i < 4; ++i)
#pragma unroll
        for (int j = 0; j < 4; ++j)
          acc[i][j] = __builtin_amdgcn_mfma_f32_16x16x32_bf16(af[i], bfv[j], acc[i][j], 0, 0, 0);
    }
    __syncthreads();
  }

  // epilogue: partial z per (i,r) row = sum_j relu(acc+gb1)*gw2, then
  // l15 butterfly (lanes differing in bits 0..3 share (quad,i,r) row).
  float zp[4][4];
#pragma unroll
  for (int i = 0; i < 4; ++i)
#pragma unroll
    for (int r = 0; r < 4; ++r) zp[i][r] = 0.f;
#pragma unroll
  for (int i = 0; i < 4; ++i)
#pragma unroll
    for (int j = 0; j < 4; ++j) {
      int col = bn + wn * 64 + j * 16 + l15;
      float bv = __bfloat162float(bias[col]);
      float w2 = __bfloat162float(gw2[col]);
#pragma unroll
      for (int r = 0; r < 4; ++r) {
        float v = fmaxf(acc[i][j][r] + bv, 0.f);
        zp[i][r] += v * w2;
      }
    }
#pragma unroll
  for (int i = 0; i < 4; ++i)
#pragma unroll
    for (int r = 0; r < 4; ++r) {
#pragma unroll
      for (int o = 1; o <= 8; o <<= 1) zp[i][r] += __shfl_xor(zp[i][r], o);
    }
  if (l15 == 0) {
#pragma unroll
    for (int i = 0; i < 4; ++i)
#pragma unroll
      for (int r = 0; r < 4; ++r)
        zsc[wm * 64 + i * 16 + quad * 4 + r][wn] = zp[i][r];
  }
  __syncthreads();
  if (tid < 128) {
    int row = bm + tid;
    if (row < M) z4[sw.y * 6592 + row] = zsc[tid][0] + zsc[tid][1];
  }
}

// ---- w_out GEMM with fused NS-way split-K combine (1D swizzled, 208 wg) ----
// P = NS partial ctx arrays, each [6592][512] bf16 at stride PSZ.
// L = [6588][8][NS] f32 row-sums.
template <int NS>
__global__ __launch_bounds__(256) void gemm128_pv(
    const __hip_bfloat16* __restrict__ P, const float* __restrict__ L,
    const __hip_bfloat16* __restrict__ Bt, const __hip_bfloat16* __restrict__ bias,
    __hip_bfloat16* __restrict__ C, int M) {
  const size_t PSZ = 3375104;
  __shared__ __bf16 As[128][72];
  __shared__ __bf16 Bs[128][72];
  int tid = threadIdx.x, lane = tid & 63, wave = tid >> 6;
  int wm = wave >> 1, wn = wave & 1;
  int l15 = lane & 15, quad = lane >> 4;
  int2 sw = swz(blockIdx.x, 208, 4);
  int bm = sw.x * 128, bn = sw.y * 128;

  f32x4_t acc[4][4];
#pragma unroll
  for (int i = 0; i < 4; ++i)
#pragma unroll
    for (int j = 0; j < 4; ++j)
#pragma unroll
      for (int r = 0; r < 4; ++r) acc[i][j][r] = 0.f;

  bf16x8_t rp[NS][4], rb[4];
  float rl[4][NS];

  auto gload = [&](int k0) {
    int h = k0 >> 6;
#pragma unroll
    for (int s = 0; s < 4; ++s) {
      int id = s * 256 + tid;
      int row = id >> 3, col = (id & 7) * 8;
      int arow = bm + row;
      if (arow < M) {
        size_t off = (size_t)arow * 512 + k0 + col;
#pragma unroll
        for (int i = 0; i < NS; ++i)
          rp[i][s] = *reinterpret_cast<const bf16x8_t*>(P + i * PSZ + off);
        const float* lp = &L[((size_t)arow * 8 + h) * NS];
#pragma unroll
        for (int i = 0; i < NS; ++i) rl[s][i] = lp[i];
      } else {
#pragma unroll
        for (int i = 0; i < NS; ++i) rp[i][s] = zero8();
        rl[s][0] = 1.f;
#pragma unroll
        for (int i = 1; i < NS; ++i) rl[s][i] = 0.f;
      }
      rb[s] = *reinterpret_cast<const bf16x8_t*>(Bt + (size_t)(bn + row) * 512 + k0 + col);
    }
  };
  auto stage = [&]() {
#pragma unroll
    for (int s = 0; s < 4; ++s) {
      int id = s * 256 + tid;
      int row = id >> 3, col = (id & 7) * 8;
      float sum = 0.f;
#pragma unroll
      for (int i = 0; i < NS; ++i) sum += rl[s][i];
      float sc = 1.0f / sum;
      bf16x8_t t;
#pragma unroll
      for (int e = 0; e < 8; ++e) {
        float v = 0.f;
#pragma unroll
        for (int i = 0; i < NS; ++i) v += rl[s][i] * (float)rp[i][s][e];
        t[e] = (__bf16)(v * sc);
      }
      *reinterpret_cast<bf16x8_t*>(&As[row][col]) = t;
      *reinterpret_cast<bf16x8_t*>(&Bs[row][col]) = rb[s];
    }
  };

  gload(0);
  for (int it = 0; it < 8; ++it) {
    stage();
    __syncthreads();
    if (it + 1 < 8) gload((it + 1) * 64);
#pragma unroll
    for (int ks = 0; ks < 2; ++ks) {
      bf16x8_t af[4], bfv[4];
#pragma unroll
      for (int i = 0; i < 4; ++i)
        af[i] = *reinterpret_cast<const bf16x8_t*>(
            &As[wm * 64 + i * 16 + l15][ks * 32 + quad * 8]);
#pragma unroll
      for (int j = 0; j < 4; ++j)
        bfv[j] = *reinterpret_cast<const bf16x8_t*>(
            &Bs[wn * 64 + j * 16 + l15][ks * 32 + quad * 8]);
#pragma unroll
      for (int i = 0; i < 4; ++i)
#pragma unroll
        for (int j = 0; j < 4; ++j)
          acc[i][j] = __builtin_amdgcn_mfma_f32_16x16x32_bf16(af[i], bfv[j], acc[i][j], 0, 0, 0);
    }
    __syncthreads();
  }

#pragma unroll
  for (int i = 0; i < 4; ++i)
#pragma unroll
    for (int j = 0; j < 4; ++j) {
      int col = bn + wn * 64 + j * 16 + l15;
      float bv = __bfloat162float(bias[col]);
#pragma unroll
      for (int r = 0; r < 4; ++r) {
        int row = bm + wm * 64 + i * 16 + quad * 4 + r;
        if (row < M)
          C[(size_t)row * 512 + col] = __float2bfloat16(acc[i][j][r] + bv);
      }
    }
}

// ---- flash attention core (LDS-staged K; Ks/PL stride 68; R22 form) --------
__device__ __forceinline__ void flash_core(
    const __hip_bfloat16* __restrict__ Qb, const __hip_bfloat16* __restrict__ Kb,
    const __hip_bfloat16* __restrict__ Vb, __hip_bfloat16* __restrict__ OUTb,
    float* __restrict__ LPb, int lns, int nsrc, int nref, int qt, int kt0,
    int ktNfull, int do_tail, __bf16 (&KsL)[2][64][68], __bf16 (&VtL)[2][64][72],
    __bf16 (&PL)[4][32][68]) {
  int h = blockIdx.y;
  int tid = threadIdx.x, lane = tid & 63, wave = tid >> 6;
  int l15 = lane & 15, quad = lane >> 4;
  int Mb = nsrc + 1;
  int qbase = qt * 128 + wave * 32;

  bf16x8_t qfr[2][2];
#pragma unroll
  for (int g = 0; g < 2; ++g) {
    int qrow = qbase + g * 16 + l15;
#pragma unroll
    for (int ks = 0; ks < 2; ++ks)
      qfr[g][ks] = (qrow < nsrc)
                       ? *reinterpret_cast<const bf16x8_t*>(
                             Qb + (size_t)qrow * 512 + h * 64 + ks * 32 + quad * 8)
                       : zero8();
  }

  f32x4_t O[2][4];
#pragma unroll
  for (int g = 0; g < 2; ++g)
#pragma unroll
    for (int j = 0; j < 4; ++j)
#pragma unroll
      for (int r = 0; r < 4; ++r) O[g][j][r] = 0.f;

  f32x4_t Lacc[2];
#pragma unroll
  for (int g = 0; g < 2; ++g)
#pragma unroll
    for (int r = 0; r < 4; ++r) Lacc[g][r] = 0.f;
  bf16x8_t ones;
#pragma unroll
  for (int t = 0; t < 8; ++t) ones[t] = (__bf16)1.0f;

  auto load64pair = [&](const __bf16* p) {
    bf16x4_t lo = *reinterpret_cast<const bf16x4_t*>(p);
    bf16x4_t hi = *reinterpret_cast<const bf16x4_t*>(p + 4);
    bf16x8_t v;
#pragma unroll
    for (int e = 0; e < 4; ++e) {
      v[e] = lo[e];
      v[4 + e] = hi[e];
    }
    return v;
  };

  bf16x8_t krA[2], v0, v1;
  auto gloadK = [&](int k0) {
    const __hip_bfloat16* base = Kb + (size_t)k0 * 64 + tid * 16;
    krA[0] = *reinterpret_cast<const bf16x8_t*>(base);
    krA[1] = *reinterpret_cast<const bf16x8_t*>(base + 8);
  };
  auto stageK = [&](int buf) {
#pragma unroll
    for (int p = 0; p < 2; ++p) {
      int lin = tid * 16 + p * 8;
      int row = lin >> 6, col = lin & 63;
      *reinterpret_cast<bf16x4_t*>(&KsL[buf][row][col]) =
          *reinterpret_cast<const bf16x4_t*>(&krA[p]);
      bf16x4_t hi;
#pragma unroll
      for (int e = 0; e < 4; ++e) hi[e] = krA[p][4 + e];
      *reinterpret_cast<bf16x4_t*>(&KsL[buf][row][col + 4]) = hi;
    }
  };
  auto loadV = [&](int k0) {
    const __hip_bfloat16* vp = Vb + (size_t)(k0 + lane) * 64 + wave * 16;
    v0 = *reinterpret_cast<const bf16x8_t*>(vp);
    v1 = *reinterpret_cast<const bf16x8_t*>(vp + 8);
  };

  int nit = ktNfull - kt0;
  if (nit > 0) {
    gloadK(kt0 * 64);
    loadV(kt0 * 64);
  }

  int buf = 0;
  for (int it = 0; it < nit; ++it) {
    int k0 = (kt0 + it) * 64;
    stageK(buf);
    {
      __bf16(*Vt)[72] = VtL[buf];
#pragma unroll
      for (int e = 0; e < 8; ++e) {
        Vt[wave * 16 + e][lane] = v0[e];
        Vt[wave * 16 + 8 + e][lane] = v1[e];
      }
    }
    __syncthreads();
    if (it + 1 < nit) {
      gloadK(k0 + 64);
      loadV(k0 + 64);
    }

    bf16x8_t kf[8];
#pragma unroll
    for (int j = 0; j < 4; ++j)
#pragma unroll
      for (int ks = 0; ks < 2; ++ks)
        kf[j * 2 + ks] = load64pair(&KsL[buf][j * 16 + l15][ks * 32 + quad * 8]);
#pragma unroll
    for (int g = 0; g < 2; ++g) {
      f32x4_t St[4];
#pragma unroll
      for (int j = 0; j < 4; ++j)
#pragma unroll
        for (int r = 0; r < 4; ++r) St[j][r] = 0.f;
#pragma unroll
      for (int j = 0; j < 4; ++j)
#pragma unroll
        for (int ks = 0; ks < 2; ++ks)
          St[j] = __builtin_amdgcn_mfma_f32_16x16x32_bf16(kf[j * 2 + ks], qfr[g][ks],
                                                          St[j], 0, 0, 0);
#pragma unroll
      for (int j = 0; j < 4; ++j) {
        bf16x4_t pk;
#pragma unroll
        for (int r = 0; r < 4; ++r) pk[r] = (__bf16)exp2f(St[j][r]);
        *reinterpret_cast<bf16x4_t*>(&PL[wave][g * 16 + l15][j * 16 + quad * 4]) = pk;
      }
    }

    bf16x8_t pa[2][2];
#pragma unroll
    for (int g = 0; g < 2; ++g)
#pragma unroll
      for (int ks = 0; ks < 2; ++ks)
        pa[g][ks] = load64pair(&PL[wave][g * 16 + l15][ks * 32 + quad * 8]);
#pragma unroll
    for (int g = 0; g < 2; ++g)
#pragma unroll
      for (int ks = 0; ks < 2; ++ks)
        Lacc[g] = __builtin_amdgcn_mfma_f32_16x16x32_bf16(pa[g][ks], ones, Lacc[g], 0, 0, 0);
#pragma unroll
    for (int j = 0; j < 4; ++j)
#pragma unroll
      for (int ks = 0; ks < 2; ++ks) {
        bf16x8_t vbf = *reinterpret_cast<const bf16x8_t*>(
            &VtL[buf][j * 16 + l15][ks * 32 + quad * 8]);
#pragma unroll
        for (int g = 0; g < 2; ++g)
          O[g][j] = __builtin_amdgcn_mfma_f32_16x16x32_bf16(pa[g][ks], vbf, O[g][j], 0, 0, 0);
      }
    __syncthreads();
    buf ^= 1;
  }

  if (do_tail) {
    int k0 = ktNfull * 64;
    __bf16(*Vt)[72] = VtL[buf];
    {
      int kr = k0 + lane;
      const __hip_bfloat16* vp = Vb + (size_t)kr * 64 + wave * 16;
      bf16x8_t t0 = (kr < nref) ? *reinterpret_cast<const bf16x8_t*>(vp) : zero8();
      bf16x8_t t1 = (kr < nref) ? *reinterpret_cast<const bf16x8_t*>(vp + 8) : zero8();
#pragma unroll
      for (int e = 0; e < 8; ++e) {
        Vt[wave * 16 + e][lane] = t0[e];
        Vt[wave * 16 + 8 + e][lane] = t1[e];
      }
    }
    bf16x8_t kf[8];
#pragma unroll
    for (int j = 0; j < 4; ++j) {
      int kcol = k0 + j * 16 + l15;
      const __hip_bfloat16* kp = Kb + (size_t)kcol * 64 + quad * 8;
      kf[j * 2] = (kcol < nref) ? *reinterpret_cast<const bf16x8_t*>(kp) : zero8();
      kf[j * 2 + 1] = (kcol < nref) ? *reinterpret_cast<const bf16x8_t*>(kp + 32) : zero8();
    }
#pragma unroll
    for (int g = 0; g < 2; ++g) {
      f32x4_t St[4];
#pragma unroll
      for (int j = 0; j < 4; ++j)
#pragma unroll
        for (int r = 0; r < 4; ++r) St[j][r] = 0.f;
#pragma unroll
      for (int j = 0; j < 4; ++j)
#pragma unroll
        for (int ks = 0; ks < 2; ++ks)
          St[j] = __builtin_amdgcn_mfma_f32_16x16x32_bf16(kf[j * 2 + ks], qfr[g][ks],
                                                          St[j], 0, 0, 0);
#pragma unroll
      for (int j = 0; j < 4; ++j) {
        bf16x4_t pk;
#pragma unroll
        for (int r = 0; r < 4; ++r) {
          int kl = k0 + j * 16 + quad * 4 + r;
          pk[r] = (__bf16)((kl < nref) ? exp2f(St[j][r]) : 0.f);
        }
        *reinterpret_cast<bf16x4_t*>(&PL[wave][g * 16 + l15][j * 16 + quad * 4]) = pk;
      }
    }
    __syncthreads();
    bf16x8_t pa[2][2];
#pragma unroll
    for (int g = 0; g < 2; ++g)
#pragma unroll
      for (int ks = 0; ks < 2; ++ks)
        pa[g][ks] = load64pair(&PL[wave][g * 16 + l15][ks * 32 + quad * 8]);
#pragma unroll
    for (int g = 0; g < 2; ++g)
#pragma unroll
      for (int ks = 0; ks < 2; ++ks)
        Lacc[g] = __builtin_amdgcn_mfma_f32_16x16x32_bf16(pa[g][ks], ones, Lacc[g], 0, 0, 0);
#pragma unroll
    for (int j = 0; j < 4; ++j)
#pragma unroll
      for (int ks = 0; ks < 2; ++ks) {
        bf16x8_t vbf =
            *reinterpret_cast<const bf16x8_t*>(&Vt[j * 16 + l15][ks * 32 + quad * 8]);
#pragma unroll
        for (int g = 0; g < 2; ++g)
          O[g][j] = __builtin_amdgcn_mfma_f32_16x16x32_bf16(pa[g][ks], vbf, O[g][j], 0, 0, 0);
      }
  }

  if (LPb && l15 == 0) {
#pragma unroll
    for (int g = 0; g < 2; ++g)
#pragma unroll
      for (int r = 0; r < 4; ++r) {
        int row = qbase + g * 16 + quad * 4 + r;
        if (row < Mb) LPb[((size_t)row * 8 + h) * lns] = Lacc[g][r];
      }
  }

#pragma unroll
  for (int g = 0; g < 2; ++g)
#pragma unroll
    for (int r = 0; r < 4; ++r) {
      int row = qbase + g * 16 + quad * 4 + r;
      if (row < Mb) {
        float inv = 1.0f / Lacc[g][r];
#pragma unroll
        for (int j = 0; j < 4; ++j)
          OUTb[(size_t)row * 512 + h * 64 + j * 16 + l15] =
              __float2bfloat16(O[g][j][r] * inv);
      }
    }
}

// all-batch flash; x = 128-row q-tile, y = head; zbase selects the K-split
// half (launched separately for per-half counter attribution).
__global__ __launch_bounds__(256, 3) void flash_all(
    const __hip_bfloat16* __restrict__ Q, const __hip_bfloat16* __restrict__ KV,
    __hip_bfloat16* __restrict__ P, float* __restrict__ L, int zbase, int nsplit) {
  const int TILE_START[4] = {0, 17, 30, 45};
  const int SRC_START[4] = {0, 2048, 3584, 5384};
  const int REF_START[4] = {0, 1900, 3948, 5348};
  const int SRC_LEN[4] = {2048, 1536, 1800, 1200};
  const int REF_LEN[4] = {1900, 2048, 1400, 1600};
  const int CS[4] = {0, 2049, 3586, 5387};
  const size_t PSZ = 3375104;
  const size_t CHS = (size_t)6948 * 64;
  __shared__ __bf16 KsL[2][64][68];
  __shared__ __bf16 VtL[2][64][72];
  __shared__ __bf16 PL[4][32][68];
  int bid = blockIdx.x;
  int b = (bid >= TILE_START[3]) ? 3 : (bid >= TILE_START[2]) ? 2 : (bid >= TILE_START[1]) ? 1 : 0;
  int qt = bid - TILE_START[b];
  int nref = REF_LEN[b];
  int full = nref >> 6, nkt = (nref + 63) >> 6, rem = nref & 63;
  int split = zbase;
  int kt0 = (nkt * split) / nsplit;
  int ktN, tail;
  if (split == nsplit - 1) { ktN = full; tail = rem > 0; }
  else { ktN = (nkt * (split + 1)) / nsplit; tail = 0; }
  int h = blockIdx.y;
  const __hip_bfloat16* Kb = KV + (size_t)h * CHS + (size_t)REF_START[b] * 64;
  const __hip_bfloat16* Vb = KV + (size_t)(8 + h) * CHS + (size_t)REF_START[b] * 64;
  __hip_bfloat16* OUT = P + (size_t)split * PSZ;
  float* LP = (nsplit == 1) ? nullptr : (L + split + (size_t)CS[b] * 8 * nsplit);
  flash_core(Q + (size_t)SRC_START[b] * 512, Kb, Vb, OUT + (size_t)CS[b] * 512, LP,
             nsplit, SRC_LEN[b], nref, qt, kt0, ktN, tail, KsL, VtL, PL);
}

// per-batch flash (path B); KVb channel-blocked with stride chs.
__global__ __launch_bounds__(256, 3) void flash_one(const __hip_bfloat16* __restrict__ Qb,
                                                    const __hip_bfloat16* __restrict__ KVb,
                                                    __hip_bfloat16* __restrict__ OUTb,
                                                    int nsrc, int nref, long chs) {
  __shared__ __bf16 KsL[2][64][68];
  __shared__ __bf16 VtL[2][64][72];
  __shared__ __bf16 PL[4][32][68];
  int h = blockIdx.y;
  const __hip_bfloat16* Kb = KVb + (size_t)h * chs;
  const __hip_bfloat16* Vb = KVb + (size_t)(8 + h) * chs;
  flash_core(Qb, Kb, Vb, OUTb, nullptr, 1, nsrc, nref, blockIdx.x, 0, nref >> 6,
             (nref & 63) > 0, KsL, VtL, PL);
}

// single-launch finalize: g = sigmoid(sum z4 + gb2); residual vectorized.
__global__ __launch_bounds__(256) void finalize_all(
    const void* __restrict__ src, const __hip_bfloat16* __restrict__ aligned,
    const float* __restrict__ z4, const __hip_bfloat16* __restrict__ gb2,
    void* __restrict__ out, const void* snf) {
  int f = sniff_f32(snf);
  int lane = threadIdx.x & 63;
  int r = blockIdx.x * 4 + (threadIdx.x >> 6);
  int b = (r >= 5387) ? 3 : (r >= 3586) ? 2 : (r >= 2049) ? 1 : 0;
  const int CS[4] = {0, 2049, 3586, 5387};
  const int NSRC[4] = {2048, 1536, 1800, 1200};
  int pos = r - CS[b];
  int c0 = lane * 8;

  float z = z4[r] + z4[6592 + r] + z4[2 * 6592 + r] + z4[3 * 6592 + r] +
            __bfloat162float(gb2[0]);
  float g = 1.f / (1.f + __expf(-z));

  const size_t GOFF = (size_t)6584 * 512;
  if (pos < NSRC[b]) {
    size_t ib = (size_t)(r - b) * 512 + c0;
    bf16x8_t av = *reinterpret_cast<const bf16x8_t*>(aligned + (size_t)r * 512 + c0);
    if (f) {
      const float* sp = (const float*)src + ib;
      f32x4_t s0 = *reinterpret_cast<const f32x4_t*>(sp);
      f32x4_t s1 = *reinterpret_cast<const f32x4_t*>(sp + 4);
      f32x4_t o0, o1;
#pragma unroll
      for (int e = 0; e < 4; ++e) {
        o0[e] = s0[e] + g * __bfloat162float(av[e]);
        o1[e] = s1[e] + g * __bfloat162float(av[4 + e]);
      }
      float* op = (float*)out + ib;
      *reinterpret_cast<f32x4_t*>(op) = o0;
      *reinterpret_cast<f32x4_t*>(op + 4) = o1;
    } else {
      bf16x8_t sv = *reinterpret_cast<const bf16x8_t*>((const __hip_bfloat16*)src + ib);
      bf16x8_t ov;
#pragma unroll
      for (int e = 0; e < 8; ++e)
        ov[e] = (__bf16)(__bfloat162float(sv[e]) + g * __bfloat162float(av[e]));
      *reinterpret_cast<bf16x8_t*>((__hip_bfloat16*)out + ib) = ov;
    }
    if (lane == 0) {
      size_t go = GOFF + b * 2048 + pos;
      if (f) ((float*)out)[go] = g;
      else ((__hip_bfloat16*)out)[go] = __float2bfloat16(g);
    }
  } else {
    for (int p = NSRC[b] + lane; p < 2048; p += 64) {
      size_t go = GOFF + b * 2048 + p;
      if (f) ((float*)out)[go] = g;
      else ((__hip_bfloat16*)out)[go] = __float2bfloat16(g);
    }
  }
}

// per-batch finalize (path B)
__global__ __launch_bounds__(256) void finalize_b(
    const void* __restrict__ src, const __hip_bfloat16* __restrict__ alnb,
    const __hip_bfloat16* __restrict__ hidb, const __hip_bfloat16* __restrict__ gw2,
    const __hip_bfloat16* __restrict__ gb2, void* __restrict__ out,
    int b, int nsrc, int src_start, const void* snf) {
  int f = sniff_f32(snf);
  int lane = threadIdx.x & 63;
  int r = blockIdx.x * 4 + (threadIdx.x >> 6);
  if (r > nsrc) return;

  float zacc = 0.f;
  const __hip_bfloat16* hrow = hidb + (size_t)r * 512;
#pragma unroll
  for (int t = 0; t < 8; ++t) {
    int c = lane + (t << 6);
    zacc += __bfloat162float(hrow[c]) * __bfloat162float(gw2[c]);
  }
  for (int o = 32; o; o >>= 1) zacc += __shfl_xor(zacc, o);
  zacc += __bfloat162float(gb2[0]);
  float g = 1.f / (1.f + __expf(-zacc));

  const size_t GOFF = (size_t)6584 * 512;
  if (r < nsrc) {
    size_t ib = (size_t)(src_start + r) * 512;
    const __hip_bfloat16* arow = alnb + (size_t)r * 512;
#pragma unroll
    for (int t = 0; t < 8; ++t) {
      int c = lane + (t << 6);
      float sv = f ? ((const float*)src)[ib + c]
                   : __bfloat162float(((const __hip_bfloat16*)src)[ib + c]);
      float val = sv + g * __bfloat162float(arow[c]);
      if (f) ((float*)out)[ib + c] = val;
      else ((__hip_bfloat16*)out)[ib + c] = __float2bfloat16(val);
    }
    if (lane == 0) {
      size_t go = GOFF + b * 2048 + r;
      if (f) ((float*)out)[go] = g;
      else ((__hip_bfloat16*)out)[go] = __float2bfloat16(g);
    }
  } else {
    for (int p = nsrc + lane; p < 2048; p += 64) {
      size_t go = GOFF + b * 2048 + p;
      if (f) ((float*)out)[go] = g;
      else ((__hip_bfloat16*)out)[go] = __float2bfloat16(g);
    }
  }
}

extern "C" void kernel_launch(void* const* d_in, const int* in_sizes, int n_in,
                              void* d_out, int out_size, void* d_ws, size_t ws_size,
                              hipStream_t stream) {
  (void)in_sizes; (void)n_in; (void)out_size;
  const void* feats_src = d_in[0];
  const void* feats_ref = d_in[2];
  const void* w_in = d_in[4];
  const void* b_in = d_in[5];
  const void* w_out = d_in[6];
  const void* b_out = d_in[7];
  const void* gw1 = d_in[8];
  const void* gb1 = d_in[9];
  const void* gw2 = d_in[10];
  const void* gb2 = d_in[11];

  const size_t F_W_IN = 16, F_B_IN = 786448, F_W_OUT = 787984, F_B_OUT = 1050128,
               F_GW1 = 1050640, F_GB1 = 1312784, F_GW2 = 1313296, F_GB2 = 1313808,
               A0 = 1313824;  // bf16-element offsets
  const size_t PSZ = 3375104;                    // one partial ctx [6592][512]
  const size_t R3E = A0 + PSZ + 7114752;         // el 11803680 (R3 == P base)
  const size_t FS0 = R3E;                        // feats bf16 overlay (A2 only)
  const size_t FR0 = R3E + 3371008;              // el 15174688
  const size_t Z4EL = 52736;                     // 4*6592 f32 in bf16 elements
  const size_t NEED_A2 = 2 * (R3E + 2 * PSZ + 210816 + Z4EL);  // 37,634,880 B
  const size_t NEED_A = 2 * (R3E + PSZ + Z4EL);                // 30,463,040 B
  const size_t NEED_B = 2 * (A0 + 4259840);                    // 11,147,328 B

  if (ws_size < NEED_B) {
    sentinel_k<<<1, 64, 0, stream>>>((float*)d_out);
    return;
  }

  __hip_bfloat16* ws = (__hip_bfloat16*)d_ws;

  const int SRC_LEN[4] = {2048, 1536, 1800, 1200};
  const int REF_LEN[4] = {1900, 2048, 1400, 1600};
  const int SRC_START[4] = {0, 2048, 3584, 5384};
  const int REF_START[4] = {0, 1900, 3948, 5348};
  dim3 blk(256);

  if (ws_size >= NEED_A) {
    __hip_bfloat16* R1 = ws + A0;         // Q then ALN [6592*512]
    __hip_bfloat16* R2 = R1 + PSZ;        // KV channel-blocked [16][6948][64]
    __hip_bfloat16* R3 = R2 + 7114752;    // CTX (NS=1) or P partial base (NS=2)
    int NS = (ws_size >= NEED_A2) ? 2 : 1;
    if (NS == 2) {
      float* L = (float*)(ws + R3E + 2 * PSZ);        // [6588][8][2] f32
      float* Z4 = (float*)(ws + R3E + 2 * PSZ + 210816);  // [4][6592] f32
      cv_all<<<dim3(4407), blk, 0, stream>>>(w_in, b_in, w_out, b_out, gw1, gb1,
                                             gw2, gb2, ws, feats_src, feats_ref, 1);
      proj2<<<dim3(648), blk, 0, stream>>>(ws + FS0, ws + FR0, ws, R1, R2, nullptr);
      flash_all<<<dim3(55, 8, 1), blk, 0, stream>>>(R1, R2, R3, L, 0, 2);
      flash_all<<<dim3(55, 8, 1), blk, 0, stream>>>(R1, R2, R3, L, 1, 2);
      gemm128_pv<2><<<dim3(208), blk, 0, stream>>>(R3, L, ws + F_W_OUT,
                                                   ws + F_B_OUT, R1, 6588);
      gate_gemm<<<dim3(208), blk, 0, stream>>>(R1, ws + F_GW1, ws + F_GB1,
                                               ws + F_GW2, Z4, 6588);
      finalize_all<<<dim3(1647), blk, 0, stream>>>(feats_src, R1, Z4, ws + F_GB2,
                                                   d_out, w_in);
    } else {
      float* Z4 = (float*)(ws + R3E + PSZ);  // [4][6592] f32 after CTX
      cv_all<<<dim3(1024), blk, 0, stream>>>(w_in, b_in, w_out, b_out, gw1, gb1,
                                             gw2, gb2, ws, nullptr, nullptr, 0);
      proj2<<<dim3(648), blk, 0, stream>>>(feats_src, feats_ref, ws, R1, R2, w_in);
      flash_all<<<dim3(55, 8, 1), blk, 0, stream>>>(R1, R2, R3, nullptr, 0, 1);
      gemm128z<<<dim3(208), blk, 0, stream>>>(R3, ws + F_W_OUT, ws + F_B_OUT, R1,
                                              6588, 1.0f, 0);
      gate_gemm<<<dim3(208), blk, 0, stream>>>(R1, ws + F_GW1, ws + F_GB1,
                                               ws + F_GW2, Z4, 6588);
      finalize_all<<<dim3(1647), blk, 0, stream>>>(feats_src, R1, Z4, ws + F_GB2,
                                                   d_out, w_in);
    }
  } else {
    cv_all<<<dim3(1024), blk, 0, stream>>>(w_in, b_in, w_out, b_out, gw1, gb1,
                                           gw2, gb2, ws, nullptr, nullptr, 0);
    __hip_bfloat16* W2 = ws + A0;        // KV channel-blocked [16][2048][64]
    __hip_bfloat16* W1 = W2 + 2097152;   // Q then ALN [2112*512]
    __hip_bfloat16* W3 = W1 + 1081344;   // CTX then HID [2112*512]
    const long CHS_B = (long)2048 * 64;
    for (int b = 0; b < 4; ++b) {
      int nsrc = SRC_LEN[b], nref = REF_LEN[b];
      gemm128<true><<<dim3((nsrc + 127) / 128, 4), blk, 0, stream>>>(
          feats_src, (long)SRC_START[b] * 512, ws + F_W_IN, ws + F_B_IN, W1, nsrc, 512,
          512, 512, CQ_SCALE, 0, 0, w_in);
      gemm128<true><<<dim3((nref + 127) / 128, 8), blk, 0, stream>>>(
          feats_ref, (long)REF_START[b] * 512, ws + F_W_IN + 262144, ws + F_B_IN + 512,
          W2, nref, 512, 512, 1024, 1.0f, 0, CHS_B, w_in);
      flash_one<<<dim3((nsrc + 128) / 128, 8), blk, 0, stream>>>(W1, W2, W3, nsrc, nref,
                                                                 CHS_B);
      gemm128<false><<<dim3((nsrc + 128) / 128, 4), blk, 0, stream>>>(
          W3, 0, ws + F_W_OUT, ws + F_B_OUT, W1, nsrc + 1, 512, 512, 512, 1.0f, 0, 0,
          nullptr);
      gemm128<false><<<dim3((nsrc + 128) / 128, 4), blk, 0, stream>>>(
          W1, 0, ws + F_GW1, ws + F_GB1, W3, nsrc + 1, 512, 512, 512, 1.0f, 1, 0,
          nullptr);
      finalize_b<<<dim3((nsrc + 4) / 4), blk, 0, stream>>>(
          feats_src, W1, W3, ws + F_GW2, ws + F_GB2, d_out, b, nsrc, SRC_START[b], w_in);
    }
  }
}

// Round 18
// 218.416 us; speedup vs baseline: 1.1580x; 1.1580x over previous
//
#include <hip/hip_runtime.h>
#include <hip/hip_bf16.h>

// ---------------------------------------------------------------------------
// GatedAttentionFusion on MI355X (gfx950). Inputs bf16 OR fp32 (ballot-probe).
//   SRC_LENS = {2048,1536,1800,1200} (sum 6584), REF_LENS = {1900,2048,1400,1600}
// R30 == R29 resubmitted (R29 bench was a GPUAcquisitionTimeout; no data).
// R29: proj2 de-starvation. R28 probe: proj2 = 44.8us, FETCH 16MB (traffic
// FIXED) but occupancy 12.5%, all pipes <15% -> latency-starved. Cause:
// runtime f flag keeps BOTH A-load paths allocated (raf fp32 staging = 32
// VGPR + dual addressing) -> VGPR 120 + 64 acc -> 2 waves/SIMD.
//  (1) gemm_core<RTF> template: RTF=false drops fp32 path (if constexpr) ->
//      proj2b/gemm128z bf16-only with __launch_bounds__(256,3) -> 3 blk/CU.
//  (2) flash re-merged into one z=2 launch (probe cost ~13us refunded).
//  pv/gate unchanged (attribution). gate_gemm (R27, verified) kept.
// Tiers: A2 (split-K flash + fused-combine w_out GEMM) / A / B / sentinel.
// ---------------------------------------------------------------------------

typedef __bf16 bf16x8_t __attribute__((ext_vector_type(8)));
typedef __bf16 bf16x4_t __attribute__((ext_vector_type(4)));
typedef float f32x4_t __attribute__((ext_vector_type(4)));
typedef float f32x2_t __attribute__((ext_vector_type(2)));

#define CQ_SCALE 0.18033688011112042f  // 0.125 * log2(e)

__device__ inline bf16x8_t zero8() {
  bf16x8_t z;
#pragma unroll
  for (int t = 0; t < 8; ++t) z[t] = (__bf16)0.0f;
  return z;
}

// wave-uniform: 1 if the tensor behind w is fp32, 0 if bf16.
__device__ __forceinline__ int sniff_f32(const void* w) {
  unsigned short u = ((const unsigned short*)w)[threadIdx.x & 63];
  return __ballot((u & 0x7F80) >= 0x3F80) != 0ULL;
}

// chunked XCD swizzle: XCD k (= bid mod 8) gets contiguous panel-major work.
// nwg must be divisible by 8. Returns (bx, by).
__device__ __forceinline__ int2 swz(int bid, int nwg, int nby) {
  int chunk = nwg >> 3;
  int w = (bid & 7) * chunk + (bid >> 3);
  return make_int2(w / nby, w % nby);
}

__global__ void sentinel_k(float* out) {
  if (threadIdx.x == 0 && blockIdx.x == 0) out[0] = 1000.0f;  // ws too small
}

// Fused conversion kernel. do_feats: blocks [0,3383) convert feats (x8
// vectorized) into the R3/P overlay; remaining blocks grid-stride the
// weight tensors. do_feats==0: all blocks do weights.
__global__ void cv_all(const void* w_in, const void* b_in, const void* w_out,
                       const void* b_out, const void* gw1, const void* gb1,
                       const void* gw2, const void* gb2,
                       __hip_bfloat16* __restrict__ ws,
                       const void* fs, const void* fr, int do_feats) {
  int f = sniff_f32(w_in);
  int bid = blockIdx.x;
  if (do_feats && bid < 3383) {
    // feats -> bf16: FS at el 11,803,680 (6584x512); FR at el 15,174,688.
    int i = bid * 256 + threadIdx.x;
    const int NFS = 421376;  // 6584*512/8
    const void* src;
    size_t dst;
    int off;
    if (i < NFS) { src = fs; dst = 11803680; off = i * 8; }
    else { src = fr; dst = 15174688; off = (i - NFS) * 8; }
    __hip_bfloat16* d = ws + dst + off;
    if (f) {
      const float* p = (const float*)src + off;
      bf16x8_t v;
#pragma unroll
      for (int e = 0; e < 8; ++e) v[e] = (__bf16)p[e];
      *reinterpret_cast<bf16x8_t*>(d) = v;
    } else {
      *reinterpret_cast<bf16x8_t*>(d) =
          *reinterpret_cast<const bf16x8_t*>((const __hip_bfloat16*)src + off);
    }
    return;
  }
  int base = do_feats ? 3383 : 0;
  int nb = gridDim.x - base;
  const size_t F_W_IN = 16, F_B_IN = 786448, F_W_OUT = 787984, F_B_OUT = 1050128,
               F_GW1 = 1050640, F_GB1 = 1312784, F_GW2 = 1313296, F_GB2 = 1313808;
  const int total = 1313793;
  for (int g = (bid - base) * 256 + threadIdx.x; g < total; g += nb * 256) {
    const void* src;
    size_t dst;
    int i;
    if (g < 786432) { src = w_in; dst = F_W_IN; i = g; }
    else if (g < 787968) { src = b_in; dst = F_B_IN; i = g - 786432; }
    else if (g < 1050112) { src = w_out; dst = F_W_OUT; i = g - 787968; }
    else if (g < 1050624) { src = b_out; dst = F_B_OUT; i = g - 1050112; }
    else if (g < 1312768) { src = gw1; dst = F_GW1; i = g - 1050624; }
    else if (g < 1313280) { src = gb1; dst = F_GB1; i = g - 1312768; }
    else if (g < 1313792) { src = gw2; dst = F_GW2; i = g - 1313280; }
    else { src = gb2; dst = F_GB2; i = g - 1313792; }
    ws[dst + i] = f ? __float2bfloat16(((const float*)src)[i])
                    : ((const __hip_bfloat16*)src)[i];
  }
}

// ---- shared GEMM core (BM=128, BN=128, BK=64): C = A·Bt + bias -------------
// RTF=true: A may be fp32 (runtime f). RTF=false: A is bf16, fp32 path
// compiled out (saves ~32 VGPR of dead staging + dual addressing).
// chs == 0: C row-major [M][ldc].  chs > 0: channel-blocked C[c][row][64].
template <bool RTF>
__device__ __forceinline__ void gemm_core(
    const void* __restrict__ A_, long aoff, const __hip_bfloat16* __restrict__ Bt,
    const __hip_bfloat16* __restrict__ bias, __hip_bfloat16* __restrict__ C,
    int M, int K, int lda, int ldc, float cscale, int relu, int f, int bm, int bn,
    long chs, __bf16 (&As)[128][72], __bf16 (&Bs)[128][72]) {
  int tid = threadIdx.x, lane = tid & 63, wave = tid >> 6;
  int wm = wave >> 1, wn = wave & 1;
  int l15 = lane & 15, quad = lane >> 4;

  f32x4_t acc[4][4];
#pragma unroll
  for (int i = 0; i < 4; ++i)
#pragma unroll
    for (int j = 0; j < 4; ++j)
#pragma unroll
      for (int r = 0; r < 4; ++r) acc[i][j][r] = 0.f;

  bf16x8_t ra[4], rb[4];
  f32x4_t raf[RTF ? 4 : 1][2];

  auto gload = [&](int k0) {
#pragma unroll
    for (int s = 0; s < 4; ++s) {
      int id = s * 256 + tid;
      int row = id >> 3, col = (id & 7) * 8;
      int arow = bm + row;
      if constexpr (RTF) {
        if (f) {
          if (arow < M) {
            const float* p = (const float*)A_ + aoff + (size_t)arow * lda + k0 + col;
            raf[s][0] = *reinterpret_cast<const f32x4_t*>(p);
            raf[s][1] = *reinterpret_cast<const f32x4_t*>(p + 4);
          } else {
#pragma unroll
            for (int e = 0; e < 4; ++e) { raf[s][0][e] = 0.f; raf[s][1][e] = 0.f; }
          }
        } else {
          ra[s] = (arow < M)
                      ? *reinterpret_cast<const bf16x8_t*>(
                            (const __hip_bfloat16*)A_ + aoff + (size_t)arow * lda + k0 + col)
                      : zero8();
        }
      } else {
        ra[s] = (arow < M)
                    ? *reinterpret_cast<const bf16x8_t*>(
                          (const __hip_bfloat16*)A_ + aoff + (size_t)arow * lda + k0 + col)
                    : zero8();
      }
      rb[s] = *reinterpret_cast<const bf16x8_t*>(Bt + (size_t)(bn + row) * 512 + k0 + col);
    }
  };
  auto stage = [&]() {
#pragma unroll
    for (int s = 0; s < 4; ++s) {
      int id = s * 256 + tid;
      int row = id >> 3, col = (id & 7) * 8;
      if constexpr (RTF) {
        if (f) {
          bf16x8_t t;
#pragma unroll
          for (int e = 0; e < 4; ++e) {
            t[e] = (__bf16)raf[s][0][e];
            t[4 + e] = (__bf16)raf[s][1][e];
          }
          *reinterpret_cast<bf16x8_t*>(&As[row][col]) = t;
        } else {
          *reinterpret_cast<bf16x8_t*>(&As[row][col]) = ra[s];
        }
      } else {
        *reinterpret_cast<bf16x8_t*>(&As[row][col]) = ra[s];
      }
      *reinterpret_cast<bf16x8_t*>(&Bs[row][col]) = rb[s];
    }
  };

  int nk = K >> 6;
  gload(0);
  for (int it = 0; it < nk; ++it) {
    stage();
    __syncthreads();
    if (it + 1 < nk) gload((it + 1) * 64);
#pragma unroll
    for (int ks = 0; ks < 2; ++ks) {
      bf16x8_t af[4], bfv[4];
#pragma unroll
      for (int i = 0; i < 4; ++i)
        af[i] = *reinterpret_cast<const bf16x8_t*>(
            &As[wm * 64 + i * 16 + l15][ks * 32 + quad * 8]);
#pragma unroll
      for (int j = 0; j < 4; ++j)
        bfv[j] = *reinterpret_cast<const bf16x8_t*>(
            &Bs[wn * 64 + j * 16 + l15][ks * 32 + quad * 8]);
#pragma unroll
      for (int i = 0; i < 4; ++i)
#pragma unroll
        for (int j = 0; j < 4; ++j)
          acc[i][j] = __builtin_amdgcn_mfma_f32_16x16x32_bf16(af[i], bfv[j], acc[i][j], 0, 0, 0);
    }
    __syncthreads();
  }

#pragma unroll
  for (int i = 0; i < 4; ++i)
#pragma unroll
    for (int j = 0; j < 4; ++j) {
      int col = bn + wn * 64 + j * 16 + l15;
      float bv = __bfloat162float(bias[col]);
#pragma unroll
      for (int r = 0; r < 4; ++r) {
        int row = bm + wm * 64 + i * 16 + quad * 4 + r;
        if (row < M) {
          float v = (acc[i][j][r] + bv) * cscale;
          if (relu) v = fmaxf(v, 0.f);
          size_t idx = chs ? ((size_t)(col >> 6) * chs + (size_t)row * 64 + (col & 63))
                           : ((size_t)row * ldc + col);
          C[idx] = __float2bfloat16(v);
        }
      }
    }
}

// bf16-only merged Q-proj (208) + KV-proj (440); A from the ws overlay.
// launch_bounds(256,3): fp32 path compiled out -> VGPR fits 3 waves/SIMD.
__global__ __launch_bounds__(256, 3) void proj2b(
    const __hip_bfloat16* __restrict__ fs, const __hip_bfloat16* __restrict__ fr,
    const __hip_bfloat16* __restrict__ ws, __hip_bfloat16* __restrict__ Q,
    __hip_bfloat16* __restrict__ KV) {
  __shared__ __bf16 As[128][72];
  __shared__ __bf16 Bs[128][72];
  const size_t F_W_IN = 16, F_B_IN = 786448;
  const long CHS = (long)6948 * 64;
  int bid = blockIdx.x;
  if (bid < 208) {
    int2 s = swz(bid, 208, 4);  // 52 x 4
    gemm_core<false>(fs, 0, ws + F_W_IN, ws + F_B_IN, Q, 6584, 512, 512, 512, CQ_SCALE,
                     0, 0, s.x * 128, s.y * 128, 0, As, Bs);
  } else {
    int2 s = swz(bid - 208, 440, 8);  // 55 x 8
    gemm_core<false>(fr, 0, ws + F_W_IN + 262144, ws + F_B_IN + 512, KV, 6948, 512, 512,
                     1024, 1.0f, 0, 0, s.x * 128, s.y * 128, CHS, As, Bs);
  }
}

// runtime-dtype merged proj (NS=1 fallback path).
__global__ __launch_bounds__(256) void proj2(
    const void* __restrict__ fs, const void* __restrict__ fr,
    const __hip_bfloat16* __restrict__ ws, __hip_bfloat16* __restrict__ Q,
    __hip_bfloat16* __restrict__ KV, const void* snf) {
  __shared__ __bf16 As[128][72];
  __shared__ __bf16 Bs[128][72];
  const size_t F_W_IN = 16, F_B_IN = 786448;
  const long CHS = (long)6948 * 64;
  int f = sniff_f32(snf);
  int bid = blockIdx.x;
  if (bid < 208) {
    int2 s = swz(bid, 208, 4);
    gemm_core<true>(fs, 0, ws + F_W_IN, ws + F_B_IN, Q, 6584, 512, 512, 512, CQ_SCALE,
                    0, f, s.x * 128, s.y * 128, 0, As, Bs);
  } else {
    int2 s = swz(bid - 208, 440, 8);
    gemm_core<true>(fr, 0, ws + F_W_IN + 262144, ws + F_B_IN + 512, KV, 6948, 512, 512,
                    1024, 1.0f, 0, f, s.x * 128, s.y * 128, CHS, As, Bs);
  }
}

// swizzled 1D-grid GEMM, A bf16, K=512, N=512 (NS=1 w_out path). nwg=208.
__global__ __launch_bounds__(256, 3) void gemm128z(
    const __hip_bfloat16* __restrict__ A, const __hip_bfloat16* __restrict__ Bt,
    const __hip_bfloat16* __restrict__ bias, __hip_bfloat16* __restrict__ C,
    int M, float cscale, int relu) {
  __shared__ __bf16 As[128][72];
  __shared__ __bf16 Bs[128][72];
  int2 s = swz(blockIdx.x, gridDim.x, 4);
  gemm_core<false>(A, 0, Bt, bias, C, M, 512, 512, 512, cscale, relu, 0,
                   s.x * 128, s.y * 128, 0, As, Bs);
}

// standalone GEMM (path B), A native (AF32) or bf16, 2D grid.
template <bool AF32>
__global__ __launch_bounds__(256) void gemm128(
    const void* __restrict__ A_, long aoff, const __hip_bfloat16* __restrict__ Bt,
    const __hip_bfloat16* __restrict__ bias, __hip_bfloat16* __restrict__ C,
    int M, int K, int lda, int ldc, float cscale, int relu, long chs,
    const void* snf) {
  __shared__ __bf16 As[128][72];
  __shared__ __bf16 Bs[128][72];
  int f = 0;
  if constexpr (AF32) f = sniff_f32(snf);
  gemm_core<AF32>(A_, aoff, Bt, bias, C, M, K, lda, ldc, cscale, relu, f,
                  blockIdx.x * 128, blockIdx.y * 128, chs, As, Bs);
}

// ---- gate GEMM: z4[cn][row] = sum over this col-block of relu(A@gw1+gb1)*gw2
// No HID materialization. 208 blocks (52x4 swizzled). Deterministic (no
// atomics): l15 shfl_xor reduce -> 2-wave LDS combine -> one write per row.
__global__ __launch_bounds__(256) void gate_gemm(
    const __hip_bfloat16* __restrict__ A, const __hip_bfloat16* __restrict__ Bt,
    const __hip_bfloat16* __restrict__ bias, const __hip_bfloat16* __restrict__ gw2,
    float* __restrict__ z4, int M) {
  __shared__ __bf16 As[128][72];
  __shared__ __bf16 Bs[128][72];
  __shared__ float zsc[128][2];
  int tid = threadIdx.x, lane = tid & 63, wave = tid >> 6;
  int wm = wave >> 1, wn = wave & 1;
  int l15 = lane & 15, quad = lane >> 4;
  int2 sw = swz(blockIdx.x, 208, 4);
  int bm = sw.x * 128, bn = sw.y * 128;

  f32x4_t acc[4][4];
#pragma unroll
  for (int i = 0; i < 4; ++i)
#pragma unroll
    for (int j = 0; j < 4; ++j)
#pragma unroll
      for (int r = 0; r < 4; ++r) acc[i][j][r] = 0.f;

  bf16x8_t ra[4], rb[4];
  auto gload = [&](int k0) {
#pragma unroll
    for (int s = 0; s < 4; ++s) {
      int id = s * 256 + tid;
      int row = id >> 3, col = (id & 7) * 8;
      int arow = bm + row;
      ra[s] = (arow < M)
                  ? *reinterpret_cast<const bf16x8_t*>(A + (size_t)arow * 512 + k0 + col)
                  : zero8();
      rb[s] = *reinterpret_cast<const bf16x8_t*>(Bt + (size_t)(bn + row) * 512 + k0 + col);
    }
  };
  auto stage = [&]() {
#pragma unroll
    for (int s = 0; s < 4; ++s) {
      int id = s * 256 + tid;
      int row = id >> 3, col = (id & 7) * 8;
      *reinterpret_cast<bf16x8_t*>(&As[row][col]) = ra[s];
      *reinterpret_cast<bf16x8_t*>(&Bs[row][col]) = rb[s];
    }
  };

  gload(0);
  for (int it = 0; it < 8; ++it) {
    stage();
    __syncthreads();
    if (it + 1 < 8) gload((it + 1) * 64);
#pragma unroll
    for (int ks = 0; ks < 2; ++ks) {
      bf16x8_t af[4], bfv[4];
#pragma unroll
      for (int i = 0; i < 4; ++i)
        af[i] = *reinterpret_cast<const bf16x8_t*>(
            &As[wm * 64 + i * 16 + l15][ks * 32 + quad * 8]);
#pragma unroll
      for (int j = 0; j < 4; ++j)
        bfv[j] = *reinterpret_cast<const bf16x8_t*>(
            &Bs[wn * 64 + j * 16 + l15][ks * 32 + quad * 8]);
#pragma unroll
      for (int i = 0; i < 4; ++i)
#pragma unroll
        for (int j = 0; j < 4; ++j)
          acc[i][j] = __builtin_amdgcn_mfma_f32_16x16x32_bf16(af[i], bfv[j], acc[i][j], 0, 0, 0);
    }
    __syncthreads();
  }

  // epilogue: partial z per (i,r) row = sum_j relu(acc+gb1)*gw2, then
  // l15 butterfly (lanes differing in bits 0..3 share (quad,i,r) row).
  float zp[4][4];
#pragma unroll
  for (int i = 0; i < 4; ++i)
#pragma unroll
    for (int r = 0; r < 4; ++r) zp[i][r] = 0.f;
#pragma unroll
  for (int i = 0; i < 4; ++i)
#pragma unroll
    for (int j = 0; j < 4; ++j) {
      int col = bn + wn * 64 + j * 16 + l15;
      float bv = __bfloat162float(bias[col]);
      float w2 = __bfloat162float(gw2[col]);
#pragma unroll
      for (int r = 0; r < 4; ++r) {
        float v = fmaxf(acc[i][j][r] + bv, 0.f);
        zp[i][r] += v * w2;
      }
    }
#pragma unroll
  for (int i = 0; i < 4; ++i)
#pragma unroll
    for (int r = 0; r < 4; ++r) {
#pragma unroll
      for (int o = 1; o <= 8; o <<= 1) zp[i][r] += __shfl_xor(zp[i][r], o);
    }
  if (l15 == 0) {
#pragma unroll
    for (int i = 0; i < 4; ++i)
#pragma unroll
      for (int r = 0; r < 4; ++r)
        zsc[wm * 64 + i * 16 + quad * 4 + r][wn] = zp[i][r];
  }
  __syncthreads();
  if (tid < 128) {
    int row = bm + tid;
    if (row < M) z4[sw.y * 6592 + row] = zsc[tid][0] + zsc[tid][1];
  }
}

// ---- w_out GEMM with fused NS-way split-K combine (1D swizzled, 208 wg) ----
// P = NS partial ctx arrays, each [6592][512] bf16 at stride PSZ.
// L = [6588][8][NS] f32 row-sums.
template <int NS>
__global__ __launch_bounds__(256) void gemm128_pv(
    const __hip_bfloat16* __restrict__ P, const float* __restrict__ L,
    const __hip_bfloat16* __restrict__ Bt, const __hip_bfloat16* __restrict__ bias,
    __hip_bfloat16* __restrict__ C, int M) {
  const size_t PSZ = 3375104;
  __shared__ __bf16 As[128][72];
  __shared__ __bf16 Bs[128][72];
  int tid = threadIdx.x, lane = tid & 63, wave = tid >> 6;
  int wm = wave >> 1, wn = wave & 1;
  int l15 = lane & 15, quad = lane >> 4;
  int2 sw = swz(blockIdx.x, 208, 4);
  int bm = sw.x * 128, bn = sw.y * 128;

  f32x4_t acc[4][4];
#pragma unroll
  for (int i = 0; i < 4; ++i)
#pragma unroll
    for (int j = 0; j < 4; ++j)
#pragma unroll
      for (int r = 0; r < 4; ++r) acc[i][j][r] = 0.f;

  bf16x8_t rp[NS][4], rb[4];
  float rl[4][NS];

  auto gload = [&](int k0) {
    int h = k0 >> 6;
#pragma unroll
    for (int s = 0; s < 4; ++s) {
      int id = s * 256 + tid;
      int row = id >> 3, col = (id & 7) * 8;
      int arow = bm + row;
      if (arow < M) {
        size_t off = (size_t)arow * 512 + k0 + col;
#pragma unroll
        for (int i = 0; i < NS; ++i)
          rp[i][s] = *reinterpret_cast<const bf16x8_t*>(P + i * PSZ + off);
        const float* lp = &L[((size_t)arow * 8 + h) * NS];
#pragma unroll
        for (int i = 0; i < NS; ++i) rl[s][i] = lp[i];
      } else {
#pragma unroll
        for (int i = 0; i < NS; ++i) rp[i][s] = zero8();
        rl[s][0] = 1.f;
#pragma unroll
        for (int i = 1; i < NS; ++i) rl[s][i] = 0.f;
      }
      rb[s] = *reinterpret_cast<const bf16x8_t*>(Bt + (size_t)(bn + row) * 512 + k0 + col);
    }
  };
  auto stage = [&]() {
#pragma unroll
    for (int s = 0; s < 4; ++s) {
      int id = s * 256 + tid;
      int row = id >> 3, col = (id & 7) * 8;
      float sum = 0.f;
#pragma unroll
      for (int i = 0; i < NS; ++i) sum += rl[s][i];
      float sc = 1.0f / sum;
      bf16x8_t t;
#pragma unroll
      for (int e = 0; e < 8; ++e) {
        float v = 0.f;
#pragma unroll
        for (int i = 0; i < NS; ++i) v += rl[s][i] * (float)rp[i][s][e];
        t[e] = (__bf16)(v * sc);
      }
      *reinterpret_cast<bf16x8_t*>(&As[row][col]) = t;
      *reinterpret_cast<bf16x8_t*>(&Bs[row][col]) = rb[s];
    }
  };

  gload(0);
  for (int it = 0; it < 8; ++it) {
    stage();
    __syncthreads();
    if (it + 1 < 8) gload((it + 1) * 64);
#pragma unroll
    for (int ks = 0; ks < 2; ++ks) {
      bf16x8_t af[4], bfv[4];
#pragma unroll
      for (int i = 0; i < 4; ++i)
        af[i] = *reinterpret_cast<const bf16x8_t*>(
            &As[wm * 64 + i * 16 + l15][ks * 32 + quad * 8]);
#pragma unroll
      for (int j = 0; j < 4; ++j)
        bfv[j] = *reinterpret_cast<const bf16x8_t*>(
            &Bs[wn * 64 + j * 16 + l15][ks * 32 + quad * 8]);
#pragma unroll
      for (int i = 0; i < 4; ++i)
#pragma unroll
        for (int j = 0; j < 4; ++j)
          acc[i][j] = __builtin_amdgcn_mfma_f32_16x16x32_bf16(af[i], bfv[j], acc[i][j], 0, 0, 0);
    }
    __syncthreads();
  }

#pragma unroll
  for (int i = 0; i < 4; ++i)
#pragma unroll
    for (int j = 0; j < 4; ++j) {
      int col = bn + wn * 64 + j * 16 + l15;
      float bv = __bfloat162float(bias[col]);
#pragma unroll
      for (int r = 0; r < 4; ++r) {
        int row = bm + wm * 64 + i * 16 + quad * 4 + r;
        if (row < M)
          C[(size_t)row * 512 + col] = __float2bfloat16(acc[i][j][r] + bv);
      }
    }
}

// ---- flash attention core (LDS-staged K; Ks/PL stride 68; R22 form) --------
__device__ __forceinline__ void flash_core(
    const __hip_bfloat16* __restrict__ Qb, const __hip_bfloat16* __restrict__ Kb,
    const __hip_bfloat16* __restrict__ Vb, __hip_bfloat16* __restrict__ OUTb,
    float* __restrict__ LPb, int lns, int nsrc, int nref, int qt, int kt0,
    int ktNfull, int do_tail, __bf16 (&KsL)[2][64][68], __bf16 (&VtL)[2][64][72],
    __bf16 (&PL)[4][32][68]) {
  int h = blockIdx.y;
  int tid = threadIdx.x, lane = tid & 63, wave = tid >> 6;
  int l15 = lane & 15, quad = lane >> 4;
  int Mb = nsrc + 1;
  int qbase = qt * 128 + wave * 32;

  bf16x8_t qfr[2][2];
#pragma unroll
  for (int g = 0; g < 2; ++g) {
    int qrow = qbase + g * 16 + l15;
#pragma unroll
    for (int ks = 0; ks < 2; ++ks)
      qfr[g][ks] = (qrow < nsrc)
                       ? *reinterpret_cast<const bf16x8_t*>(
                             Qb + (size_t)qrow * 512 + h * 64 + ks * 32 + quad * 8)
                       : zero8();
  }

  f32x4_t O[2][4];
#pragma unroll
  for (int g = 0; g < 2; ++g)
#pragma unroll
    for (int j = 0; j < 4; ++j)
#pragma unroll
      for (int r = 0; r < 4; ++r) O[g][j][r] = 0.f;

  f32x4_t Lacc[2];
#pragma unroll
  for (int g = 0; g < 2; ++g)
#pragma unroll
    for (int r = 0; r < 4; ++r) Lacc[g][r] = 0.f;
  bf16x8_t ones;
#pragma unroll
  for (int t = 0; t < 8; ++t) ones[t] = (__bf16)1.0f;

  auto load64pair = [&](const __bf16* p) {
    bf16x4_t lo = *reinterpret_cast<const bf16x4_t*>(p);
    bf16x4_t hi = *reinterpret_cast<const bf16x4_t*>(p + 4);
    bf16x8_t v;
#pragma unroll
    for (int e = 0; e < 4; ++e) {
      v[e] = lo[e];
      v[4 + e] = hi[e];
    }
    return v;
  };

  bf16x8_t krA[2], v0, v1;
  auto gloadK = [&](int k0) {
    const __hip_bfloat16* base = Kb + (size_t)k0 * 64 + tid * 16;
    krA[0] = *reinterpret_cast<const bf16x8_t*>(base);
    krA[1] = *reinterpret_cast<const bf16x8_t*>(base + 8);
  };
  auto stageK = [&](int buf) {
#pragma unroll
    for (int p = 0; p < 2; ++p) {
      int lin = tid * 16 + p * 8;
      int row = lin >> 6, col = lin & 63;
      *reinterpret_cast<bf16x4_t*>(&KsL[buf][row][col]) =
          *reinterpret_cast<const bf16x4_t*>(&krA[p]);
      bf16x4_t hi;
#pragma unroll
      for (int e = 0; e < 4; ++e) hi[e] = krA[p][4 + e];
      *reinterpret_cast<bf16x4_t*>(&KsL[buf][row][col + 4]) = hi;
    }
  };
  auto loadV = [&](int k0) {
    const __hip_bfloat16* vp = Vb + (size_t)(k0 + lane) * 64 + wave * 16;
    v0 = *reinterpret_cast<const bf16x8_t*>(vp);
    v1 = *reinterpret_cast<const bf16x8_t*>(vp + 8);
  };

  int nit = ktNfull - kt0;
  if (nit > 0) {
    gloadK(kt0 * 64);
    loadV(kt0 * 64);
  }

  int buf = 0;
  for (int it = 0; it < nit; ++it) {
    int k0 = (kt0 + it) * 64;
    stageK(buf);
    {
      __bf16(*Vt)[72] = VtL[buf];
#pragma unroll
      for (int e = 0; e < 8; ++e) {
        Vt[wave * 16 + e][lane] = v0[e];
        Vt[wave * 16 + 8 + e][lane] = v1[e];
      }
    }
    __syncthreads();
    if (it + 1 < nit) {
      gloadK(k0 + 64);
      loadV(k0 + 64);
    }

    bf16x8_t kf[8];
#pragma unroll
    for (int j = 0; j < 4; ++j)
#pragma unroll
      for (int ks = 0; ks < 2; ++ks)
        kf[j * 2 + ks] = load64pair(&KsL[buf][j * 16 + l15][ks * 32 + quad * 8]);
#pragma unroll
    for (int g = 0; g < 2; ++g) {
      f32x4_t St[4];
#pragma unroll
      for (int j = 0; j < 4; ++j)
#pragma unroll
        for (int r = 0; r < 4; ++r) St[j][r] = 0.f;
#pragma unroll
      for (int j = 0; j < 4; ++j)
#pragma unroll
        for (int ks = 0; ks < 2; ++ks)
          St[j] = __builtin_amdgcn_mfma_f32_16x16x32_bf16(kf[j * 2 + ks], qfr[g][ks],
                                                          St[j], 0, 0, 0);
#pragma unroll
      for (int j = 0; j < 4; ++j) {
        bf16x4_t pk;
#pragma unroll
        for (int r = 0; r < 4; ++r) pk[r] = (__bf16)exp2f(St[j][r]);
        *reinterpret_cast<bf16x4_t*>(&PL[wave][g * 16 + l15][j * 16 + quad * 4]) = pk;
      }
    }

    bf16x8_t pa[2][2];
#pragma unroll
    for (int g = 0; g < 2; ++g)
#pragma unroll
      for (int ks = 0; ks < 2; ++ks)
        pa[g][ks] = load64pair(&PL[wave][g * 16 + l15][ks * 32 + quad * 8]);
#pragma unroll
    for (int g = 0; g < 2; ++g)
#pragma unroll
      for (int ks = 0; ks < 2; ++ks)
        Lacc[g] = __builtin_amdgcn_mfma_f32_16x16x32_bf16(pa[g][ks], ones, Lacc[g], 0, 0, 0);
#pragma unroll
    for (int j = 0; j < 4; ++j)
#pragma unroll
      for (int ks = 0; ks < 2; ++ks) {
        bf16x8_t vbf = *reinterpret_cast<const bf16x8_t*>(
            &VtL[buf][j * 16 + l15][ks * 32 + quad * 8]);
#pragma unroll
        for (int g = 0; g < 2; ++g)
          O[g][j] = __builtin_amdgcn_mfma_f32_16x16x32_bf16(pa[g][ks], vbf, O[g][j], 0, 0, 0);
      }
    __syncthreads();
    buf ^= 1;
  }

  if (do_tail) {
    int k0 = ktNfull * 64;
    __bf16(*Vt)[72] = VtL[buf];
    {
      int kr = k0 + lane;
      const __hip_bfloat16* vp = Vb + (size_t)kr * 64 + wave * 16;
      bf16x8_t t0 = (kr < nref) ? *reinterpret_cast<const bf16x8_t*>(vp) : zero8();
      bf16x8_t t1 = (kr < nref) ? *reinterpret_cast<const bf16x8_t*>(vp + 8) : zero8();
#pragma unroll
      for (int e = 0; e < 8; ++e) {
        Vt[wave * 16 + e][lane] = t0[e];
        Vt[wave * 16 + 8 + e][lane] = t1[e];
      }
    }
    bf16x8_t kf[8];
#pragma unroll
    for (int j = 0; j < 4; ++j) {
      int kcol = k0 + j * 16 + l15;
      const __hip_bfloat16* kp = Kb + (size_t)kcol * 64 + quad * 8;
      kf[j * 2] = (kcol < nref) ? *reinterpret_cast<const bf16x8_t*>(kp) : zero8();
      kf[j * 2 + 1] = (kcol < nref) ? *reinterpret_cast<const bf16x8_t*>(kp + 32) : zero8();
    }
#pragma unroll
    for (int g = 0; g < 2; ++g) {
      f32x4_t St[4];
#pragma unroll
      for (int j = 0; j < 4; ++j)
#pragma unroll
        for (int r = 0; r < 4; ++r) St[j][r] = 0.f;
#pragma unroll
      for (int j = 0; j < 4; ++j)
#pragma unroll
        for (int ks = 0; ks < 2; ++ks)
          St[j] = __builtin_amdgcn_mfma_f32_16x16x32_bf16(kf[j * 2 + ks], qfr[g][ks],
                                                          St[j], 0, 0, 0);
#pragma unroll
      for (int j = 0; j < 4; ++j) {
        bf16x4_t pk;
#pragma unroll
        for (int r = 0; r < 4; ++r) {
          int kl = k0 + j * 16 + quad * 4 + r;
          pk[r] = (__bf16)((kl < nref) ? exp2f(St[j][r]) : 0.f);
        }
        *reinterpret_cast<bf16x4_t*>(&PL[wave][g * 16 + l15][j * 16 + quad * 4]) = pk;
      }
    }
    __syncthreads();
    bf16x8_t pa[2][2];
#pragma unroll
    for (int g = 0; g < 2; ++g)
#pragma unroll
      for (int ks = 0; ks < 2; ++ks)
        pa[g][ks] = load64pair(&PL[wave][g * 16 + l15][ks * 32 + quad * 8]);
#pragma unroll
    for (int g = 0; g < 2; ++g)
#pragma unroll
      for (int ks = 0; ks < 2; ++ks)
        Lacc[g] = __builtin_amdgcn_mfma_f32_16x16x32_bf16(pa[g][ks], ones, Lacc[g], 0, 0, 0);
#pragma unroll
    for (int j = 0; j < 4; ++j)
#pragma unroll
      for (int ks = 0; ks < 2; ++ks) {
        bf16x8_t vbf =
            *reinterpret_cast<const bf16x8_t*>(&Vt[j * 16 + l15][ks * 32 + quad * 8]);
#pragma unroll
        for (int g = 0; g < 2; ++g)
          O[g][j] = __builtin_amdgcn_mfma_f32_16x16x32_bf16(pa[g][ks], vbf, O[g][j], 0, 0, 0);
      }
  }

  if (LPb && l15 == 0) {
#pragma unroll
    for (int g = 0; g < 2; ++g)
#pragma unroll
      for (int r = 0; r < 4; ++r) {
        int row = qbase + g * 16 + quad * 4 + r;
        if (row < Mb) LPb[((size_t)row * 8 + h) * lns] = Lacc[g][r];
      }
  }

#pragma unroll
  for (int g = 0; g < 2; ++g)
#pragma unroll
    for (int r = 0; r < 4; ++r) {
      int row = qbase + g * 16 + quad * 4 + r;
      if (row < Mb) {
        float inv = 1.0f / Lacc[g][r];
#pragma unroll
        for (int j = 0; j < 4; ++j)
          OUTb[(size_t)row * 512 + h * 64 + j * 16 + l15] =
              __float2bfloat16(O[g][j][r] * inv);
      }
    }
}

// all-batch flash; x = 128-row q-tile, y = head, z = K-split half (+zbase).
__global__ __launch_bounds__(256, 3) void flash_all(
    const __hip_bfloat16* __restrict__ Q, const __hip_bfloat16* __restrict__ KV,
    __hip_bfloat16* __restrict__ P, float* __restrict__ L, int zbase, int nsplit) {
  const int TILE_START[4] = {0, 17, 30, 45};
  const int SRC_START[4] = {0, 2048, 3584, 5384};
  const int REF_START[4] = {0, 1900, 3948, 5348};
  const int SRC_LEN[4] = {2048, 1536, 1800, 1200};
  const int REF_LEN[4] = {1900, 2048, 1400, 1600};
  const int CS[4] = {0, 2049, 3586, 5387};
  const size_t PSZ = 3375104;
  const size_t CHS = (size_t)6948 * 64;
  __shared__ __bf16 KsL[2][64][68];
  __shared__ __bf16 VtL[2][64][72];
  __shared__ __bf16 PL[4][32][68];
  int bid = blockIdx.x;
  int b = (bid >= TILE_START[3]) ? 3 : (bid >= TILE_START[2]) ? 2 : (bid >= TILE_START[1]) ? 1 : 0;
  int qt = bid - TILE_START[b];
  int nref = REF_LEN[b];
  int full = nref >> 6, nkt = (nref + 63) >> 6, rem = nref & 63;
  int split = zbase + blockIdx.z;
  int kt0 = (nkt * split) / nsplit;
  int ktN, tail;
  if (split == nsplit - 1) { ktN = full; tail = rem > 0; }
  else { ktN = (nkt * (split + 1)) / nsplit; tail = 0; }
  int h = blockIdx.y;
  const __hip_bfloat16* Kb = KV + (size_t)h * CHS + (size_t)REF_START[b] * 64;
  const __hip_bfloat16* Vb = KV + (size_t)(8 + h) * CHS + (size_t)REF_START[b] * 64;
  __hip_bfloat16* OUT = P + (size_t)split * PSZ;
  float* LP = (nsplit == 1) ? nullptr : (L + split + (size_t)CS[b] * 8 * nsplit);
  flash_core(Q + (size_t)SRC_START[b] * 512, Kb, Vb, OUT + (size_t)CS[b] * 512, LP,
             nsplit, SRC_LEN[b], nref, qt, kt0, ktN, tail, KsL, VtL, PL);
}

// per-batch flash (path B); KVb channel-blocked with stride chs.
__global__ __launch_bounds__(256, 3) void flash_one(const __hip_bfloat16* __restrict__ Qb,
                                                    const __hip_bfloat16* __restrict__ KVb,
                                                    __hip_bfloat16* __restrict__ OUTb,
                                                    int nsrc, int nref, long chs) {
  __shared__ __bf16 KsL[2][64][68];
  __shared__ __bf16 VtL[2][64][72];
  __shared__ __bf16 PL[4][32][68];
  int h = blockIdx.y;
  const __hip_bfloat16* Kb = KVb + (size_t)h * chs;
  const __hip_bfloat16* Vb = KVb + (size_t)(8 + h) * chs;
  flash_core(Qb, Kb, Vb, OUTb, nullptr, 1, nsrc, nref, blockIdx.x, 0, nref >> 6,
             (nref & 63) > 0, KsL, VtL, PL);
}

// single-launch finalize: g = sigmoid(sum z4 + gb2); residual vectorized.
__global__ __launch_bounds__(256) void finalize_all(
    const void* __restrict__ src, const __hip_bfloat16* __restrict__ aligned,
    const float* __restrict__ z4, const __hip_bfloat16* __restrict__ gb2,
    void* __restrict__ out, const void* snf) {
  int f = sniff_f32(snf);
  int lane = threadIdx.x & 63;
  int r = blockIdx.x * 4 + (threadIdx.x >> 6);
  int b = (r >= 5387) ? 3 : (r >= 3586) ? 2 : (r >= 2049) ? 1 : 0;
  const int CS[4] = {0, 2049, 3586, 5387};
  const int NSRC[4] = {2048, 1536, 1800, 1200};
  int pos = r - CS[b];
  int c0 = lane * 8;

  float z = z4[r] + z4[6592 + r] + z4[2 * 6592 + r] + z4[3 * 6592 + r] +
            __bfloat162float(gb2[0]);
  float g = 1.f / (1.f + __expf(-z));

  const size_t GOFF = (size_t)6584 * 512;
  if (pos < NSRC[b]) {
    size_t ib = (size_t)(r - b) * 512 + c0;
    bf16x8_t av = *reinterpret_cast<const bf16x8_t*>(aligned + (size_t)r * 512 + c0);
    if (f) {
      const float* sp = (const float*)src + ib;
      f32x4_t s0 = *reinterpret_cast<const f32x4_t*>(sp);
      f32x4_t s1 = *reinterpret_cast<const f32x4_t*>(sp + 4);
      f32x4_t o0, o1;
#pragma unroll
      for (int e = 0; e < 4; ++e) {
        o0[e] = s0[e] + g * __bfloat162float(av[e]);
        o1[e] = s1[e] + g * __bfloat162float(av[4 + e]);
      }
      float* op = (float*)out + ib;
      *reinterpret_cast<f32x4_t*>(op) = o0;
      *reinterpret_cast<f32x4_t*>(op + 4) = o1;
    } else {
      bf16x8_t sv = *reinterpret_cast<const bf16x8_t*>((const __hip_bfloat16*)src + ib);
      bf16x8_t ov;
#pragma unroll
      for (int e = 0; e < 8; ++e)
        ov[e] = (__bf16)(__bfloat162float(sv[e]) + g * __bfloat162float(av[e]));
      *reinterpret_cast<bf16x8_t*>((__hip_bfloat16*)out + ib) = ov;
    }
    if (lane == 0) {
      size_t go = GOFF + b * 2048 + pos;
      if (f) ((float*)out)[go] = g;
      else ((__hip_bfloat16*)out)[go] = __float2bfloat16(g);
    }
  } else {
    for (int p = NSRC[b] + lane; p < 2048; p += 64) {
      size_t go = GOFF + b * 2048 + p;
      if (f) ((float*)out)[go] = g;
      else ((__hip_bfloat16*)out)[go] = __float2bfloat16(g);
    }
  }
}

// per-batch finalize (path B)
__global__ __launch_bounds__(256) void finalize_b(
    const void* __restrict__ src, const __hip_bfloat16* __restrict__ alnb,
    const __hip_bfloat16* __restrict__ hidb, const __hip_bfloat16* __restrict__ gw2,
    const __hip_bfloat16* __restrict__ gb2, void* __restrict__ out,
    int b, int nsrc, int src_start, const void* snf) {
  int f = sniff_f32(snf);
  int lane = threadIdx.x & 63;
  int r = blockIdx.x * 4 + (threadIdx.x >> 6);
  if (r > nsrc) return;

  float zacc = 0.f;
  const __hip_bfloat16* hrow = hidb + (size_t)r * 512;
#pragma unroll
  for (int t = 0; t < 8; ++t) {
    int c = lane + (t << 6);
    zacc += __bfloat162float(hrow[c]) * __bfloat162float(gw2[c]);
  }
  for (int o = 32; o; o >>= 1) zacc += __shfl_xor(zacc, o);
  zacc += __bfloat162float(gb2[0]);
  float g = 1.f / (1.f + __expf(-zacc));

  const size_t GOFF = (size_t)6584 * 512;
  if (r < nsrc) {
    size_t ib = (size_t)(src_start + r) * 512;
    const __hip_bfloat16* arow = alnb + (size_t)r * 512;
#pragma unroll
    for (int t = 0; t < 8; ++t) {
      int c = lane + (t << 6);
      float sv = f ? ((const float*)src)[ib + c]
                   : __bfloat162float(((const __hip_bfloat16*)src)[ib + c]);
      float val = sv + g * __bfloat162float(arow[c]);
      if (f) ((float*)out)[ib + c] = val;
      else ((__hip_bfloat16*)out)[ib + c] = __float2bfloat16(val);
    }
    if (lane == 0) {
      size_t go = GOFF + b * 2048 + r;
      if (f) ((float*)out)[go] = g;
      else ((__hip_bfloat16*)out)[go] = __float2bfloat16(g);
    }
  } else {
    for (int p = nsrc + lane; p < 2048; p += 64) {
      size_t go = GOFF + b * 2048 + p;
      if (f) ((float*)out)[go] = g;
      else ((__hip_bfloat16*)out)[go] = __float2bfloat16(g);
    }
  }
}

extern "C" void kernel_launch(void* const* d_in, const int* in_sizes, int n_in,
                              void* d_out, int out_size, void* d_ws, size_t ws_size,
                              hipStream_t stream) {
  (void)in_sizes; (void)n_in; (void)out_size;
  const void* feats_src = d_in[0];
  const void* feats_ref = d_in[2];
  const void* w_in = d_in[4];
  const void* b_in = d_in[5];
  const void* w_out = d_in[6];
  const void* b_out = d_in[7];
  const void* gw1 = d_in[8];
  const void* gb1 = d_in[9];
  const void* gw2 = d_in[10];
  const void* gb2 = d_in[11];

  const size_t F_W_IN = 16, F_B_IN = 786448, F_W_OUT = 787984, F_B_OUT = 1050128,
               F_GW1 = 1050640, F_GB1 = 1312784, F_GW2 = 1313296, F_GB2 = 1313808,
               A0 = 1313824;  // bf16-element offsets
  const size_t PSZ = 3375104;                    // one partial ctx [6592][512]
  const size_t R3E = A0 + PSZ + 7114752;         // el 11803680 (R3 == P base)
  const size_t FS0 = R3E;                        // feats bf16 overlay (A2 only)
  const size_t FR0 = R3E + 3371008;              // el 15174688
  const size_t Z4EL = 52736;                     // 4*6592 f32 in bf16 elements
  const size_t NEED_A2 = 2 * (R3E + 2 * PSZ + 210816 + Z4EL);  // 37,634,880 B
  const size_t NEED_A = 2 * (R3E + PSZ + Z4EL);                // 30,463,040 B
  const size_t NEED_B = 2 * (A0 + 4259840);                    // 11,147,328 B

  if (ws_size < NEED_B) {
    sentinel_k<<<1, 64, 0, stream>>>((float*)d_out);
    return;
  }

  __hip_bfloat16* ws = (__hip_bfloat16*)d_ws;

  const int SRC_LEN[4] = {2048, 1536, 1800, 1200};
  const int REF_LEN[4] = {1900, 2048, 1400, 1600};
  const int SRC_START[4] = {0, 2048, 3584, 5384};
  const int REF_START[4] = {0, 1900, 3948, 5348};
  dim3 blk(256);

  if (ws_size >= NEED_A) {
    __hip_bfloat16* R1 = ws + A0;         // Q then ALN [6592*512]
    __hip_bfloat16* R2 = R1 + PSZ;        // KV channel-blocked [16][6948][64]
    __hip_bfloat16* R3 = R2 + 7114752;    // CTX (NS=1) or P partial base (NS=2)
    int NS = (ws_size >= NEED_A2) ? 2 : 1;
    if (NS == 2) {
      float* L = (float*)(ws + R3E + 2 * PSZ);        // [6588][8][2] f32
      float* Z4 = (float*)(ws + R3E + 2 * PSZ + 210816);  // [4][6592] f32
      cv_all<<<dim3(4407), blk, 0, stream>>>(w_in, b_in, w_out, b_out, gw1, gb1,
                                             gw2, gb2, ws, feats_src, feats_ref, 1);
      proj2b<<<dim3(648), blk, 0, stream>>>(ws + FS0, ws + FR0, ws, R1, R2);
      flash_all<<<dim3(55, 8, 2), blk, 0, stream>>>(R1, R2, R3, L, 0, 2);
      gemm128_pv<2><<<dim3(208), blk, 0, stream>>>(R3, L, ws + F_W_OUT,
                                                   ws + F_B_OUT, R1, 6588);
      gate_gemm<<<dim3(208), blk, 0, stream>>>(R1, ws + F_GW1, ws + F_GB1,
                                               ws + F_GW2, Z4, 6588);
      finalize_all<<<dim3(1647), blk, 0, stream>>>(feats_src, R1, Z4, ws + F_GB2,
                                                   d_out, w_in);
    } else {
      float* Z4 = (float*)(ws + R3E + PSZ);  // [4][6592] f32 after CTX
      cv_all<<<dim3(1024), blk, 0, stream>>>(w_in, b_in, w_out, b_out, gw1, gb1,
                                             gw2, gb2, ws, nullptr, nullptr, 0);
      proj2<<<dim3(648), blk, 0, stream>>>(feats_src, feats_ref, ws, R1, R2, w_in);
      flash_all<<<dim3(55, 8, 1), blk, 0, stream>>>(R1, R2, R3, nullptr, 0, 1);
      gemm128z<<<dim3(208), blk, 0, stream>>>(R3, ws + F_W_OUT, ws + F_B_OUT, R1,
                                              6588, 1.0f, 0);
      gate_gemm<<<dim3(208), blk, 0, stream>>>(R1, ws + F_GW1, ws + F_GB1,
                                               ws + F_GW2, Z4, 6588);
      finalize_all<<<dim3(1647), blk, 0, stream>>>(feats_src, R1, Z4, ws + F_GB2,
                                                   d_out, w_in);
    }
  } else {
    cv_all<<<dim3(1024), blk, 0, stream>>>(w_in, b_in, w_out, b_out, gw1, gb1,
                                           gw2, gb2, ws, nullptr, nullptr, 0);
    __hip_bfloat16* W2 = ws + A0;        // KV channel-blocked [16][2048][64]
    __hip_bfloat16* W1 = W2 + 2097152;   // Q then ALN [2112*512]
    __hip_bfloat16* W3 = W1 + 1081344;   // CTX then HID [2112*512]
    const long CHS_B = (long)2048 * 64;
    for (int b = 0; b < 4; ++b) {
      int nsrc = SRC_LEN[b], nref = REF_LEN[b];
      gemm128<true><<<dim3((nsrc + 127) / 128, 4), blk, 0, stream>>>(
          feats_src, (long)SRC_START[b] * 512, ws + F_W_IN, ws + F_B_IN, W1, nsrc, 512,
          512, 512, CQ_SCALE, 0, 0, w_in);
      gemm128<true><<<dim3((nref + 127) / 128, 8), blk, 0, stream>>>(
          feats_ref, (long)REF_START[b] * 512, ws + F_W_IN + 262144, ws + F_B_IN + 512,
          W2, nref, 512, 512, 1024, 1.0f, 0, CHS_B, w_in);
      flash_one<<<dim3((nsrc + 128) / 128, 8), blk, 0, stream>>>(W1, W2, W3, nsrc, nref,
                                                                 CHS_B);
      gemm128<false><<<dim3((nsrc + 128) / 128, 4), blk, 0, stream>>>(
          W3, 0, ws + F_W_OUT, ws + F_B_OUT, W1, nsrc + 1, 512, 512, 512, 1.0f, 0, 0,
          nullptr);
      gemm128<false><<<dim3((nsrc + 128) / 128, 4), blk, 0, stream>>>(
          W1, 0, ws + F_GW1, ws + F_GB1, W3, nsrc + 1, 512, 512, 512, 1.0f, 1, 0,
          nullptr);
      finalize_b<<<dim3((nsrc + 4) / 4), blk, 0, stream>>>(
          feats_src, W1, W3, ws + F_GW2, ws + F_GB2, d_out, b, nsrc, SRC_START[b], w_in);
    }
  }
}